// Round 12
// baseline (106.451 us; speedup 1.0000x reference)
//
#include <hip/hip_runtime.h>
#include <hip/hip_bf16.h>

#define BATCH  2
#define SEQ    2048
#define DMODEL 1024
#define NHEAD  16
#define HD     64
#define BH     (BATCH * NHEAD)

typedef __attribute__((ext_vector_type(8))) short s8v;    // 8 bf16 = 4 VGPRs (MFMA A/B frag)
typedef __attribute__((ext_vector_type(16))) float f16v;  // 32x32 MFMA C/D frag

// sqrt(0.125 * log2(e)): folded QK^T scale (beta^2 = 0.18033688)
#define QK_BETA 0.42466089f

__device__ inline unsigned short bf16_rne(float f) {
    unsigned u = __builtin_bit_cast(unsigned, f);
    u += 0x7FFFu + ((u >> 16) & 1u);
    return (unsigned short)(u >> 16);
}

// pack two f32 -> u32 of 2 bf16 via hardware v_cvt_pk_bf16_f32 (RNE).
// memcpy, not bit_cast (r5: __hip_bfloat162 not trivially copyable here).
__device__ __forceinline__ unsigned pk_bf16(float lo, float hi) {
    __hip_bfloat162 h = __float22bfloat162_rn(make_float2(lo, hi));
    unsigned u;
    __builtin_memcpy(&u, &h, 4);
    return u;
}

// ---------------------------------------------------------------------------
// Prep v4 [verbatim round-11, verified passing]: x fp32 -> xb bf16 scaled by
// QK_BETA (Q/K path) and xbT bf16 unscaled [bh][d][s] (V path).
// ---------------------------------------------------------------------------
__global__ __launch_bounds__(256) void prep_kernel(const float* __restrict__ x,
                                                   unsigned short* __restrict__ xb,
                                                   unsigned short* __restrict__ xbT) {
    __shared__ unsigned short tileT[64 * 40];
    const int id = blockIdx.x;
    const int bh = id & (BH - 1);
    const int st = id >> 5;                    // s-tile 0..63
    const int b = bh >> 4, h = bh & (NHEAD - 1);
    const int s0 = st * 32;
    const int tid = threadIdx.x;
    const int c4 = tid & 15, r16 = tid >> 4;

    const size_t off0 = (size_t)(b * SEQ + s0 + r16) * DMODEL + h * HD + c4 * 4;
    const size_t off1 = (size_t)(b * SEQ + s0 + 16 + r16) * DMODEL + h * HD + c4 * 4;
    const float4 v0 = *(const float4*)(x + off0);
    const float4 v1 = *(const float4*)(x + off1);

    {
        uint2 u;
        u.x = pk_bf16(v0.x * QK_BETA, v0.y * QK_BETA);
        u.y = pk_bf16(v0.z * QK_BETA, v0.w * QK_BETA);
        *(uint2*)(xb + off0) = u;
        u.x = pk_bf16(v1.x * QK_BETA, v1.y * QK_BETA);
        u.y = pk_bf16(v1.z * QK_BETA, v1.w * QK_BETA);
        *(uint2*)(xb + off1) = u;
    }
    {
        const int d0 = c4 * 4;
        unsigned short* t0 = tileT + r16;
        t0[(d0 + 0) * 40] = bf16_rne(v0.x);
        t0[(d0 + 1) * 40] = bf16_rne(v0.y);
        t0[(d0 + 2) * 40] = bf16_rne(v0.z);
        t0[(d0 + 3) * 40] = bf16_rne(v0.w);
        unsigned short* t1 = tileT + 16 + r16;
        t1[(d0 + 0) * 40] = bf16_rne(v1.x);
        t1[(d0 + 1) * 40] = bf16_rne(v1.y);
        t1[(d0 + 2) * 40] = bf16_rne(v1.z);
        t1[(d0 + 3) * 40] = bf16_rne(v1.w);
    }
    __syncthreads();
    {
        const int d = tid >> 2;
        const int sq = (tid & 3) * 8;
        const s8v o = *(const s8v*)(tileT + d * 40 + sq);
        *(s8v*)(xbT + (size_t)(bh * HD + d) * SEQ + s0 + sq) = o;
    }
}

// ---------------------------------------------------------------------------
// Stage one 64x64 K tile + 64x64 V^T tile into LDS buffer at bufoff.
// [verbatim round-1, verified passing]
// ---------------------------------------------------------------------------
__device__ __forceinline__ void stage_tile(const unsigned short* __restrict__ xbh,
                                           const unsigned short* __restrict__ xTh,
                                           char* lds, int bufoff, int k0,
                                           int w, int sr, int sc) {
    if (w < 2) {
#pragma unroll
        for (int i = 0; i < 4; ++i) {
            const int r = w * 32 + i * 8 + sr;
            const unsigned short* gsrc =
                xbh + (size_t)(k0 + r) * DMODEL + ((sc ^ (r & 7)) * 8);
            const int loff = __builtin_amdgcn_readfirstlane(bufoff + (w * 32 + i * 8) * 128);
            __builtin_amdgcn_global_load_lds(
                (const __attribute__((address_space(1))) void*)gsrc,
                (__attribute__((address_space(3))) void*)(lds + loff), 16, 0, 0);
        }
    } else {
#pragma unroll
        for (int i = 0; i < 4; ++i) {
            const int d = (w - 2) * 32 + i * 8 + sr;
            const unsigned short* gsrc =
                xTh + (size_t)d * SEQ + k0 + ((sc ^ (d & 7)) * 8);
            const int loff =
                __builtin_amdgcn_readfirstlane(bufoff + 8192 + ((w - 2) * 32 + i * 8) * 128);
            __builtin_amdgcn_global_load_lds(
                (const __attribute__((address_space(1))) void*)gsrc,
                (__attribute__((address_space(3))) void*)(lds + loff), 16, 0, 0);
        }
    }
}

// ---------------------------------------------------------------------------
// Flash attention, bf16 MFMA 32x32x16 (halves LDS bytes per MAC vs 16x16x32
// — r8/r9 evidence: loop is LDS-issue-bound). Swapped QK^T: C[k][q].
// Block = 4 waves x 32 q-rows = 128 q. Grid 512 = 2 blocks/CU; pair (j, j+8)
// -> constant 34 iters/CU, longest-first.
// Sync template verbatim r6/r9 (verified x3): single barrier per k-tile,
// absolute-parity dbuf, stage-after-barrier, per-wave P scratch (no barrier).
// LDS 48KB: dbuf 2x16K + P scratch 4 x 4K ([q:32][kgroup:8][16B], XOR-swz).
// Mask: per-lane klocal <= qlim with wave-uniform full/dead fast paths.
// ---------------------------------------------------------------------------
__global__ __launch_bounds__(256, 2) void flash_kernel(const unsigned short* __restrict__ xb,
                                                       const unsigned short* __restrict__ xbT,
                                                       float* __restrict__ out) {
    __shared__ __align__(16) char lds[49152];

    const int id = blockIdx.x;
    const int bh = id & (BH - 1);
    const int j = id >> 5;                     // 0..15
    const int qt = (j < 8) ? (15 - j) : (j - 8);
    const int b = bh >> 4, h = bh & (NHEAD - 1);
    const int tid = threadIdx.x;
    const int w = tid >> 6;                            // wave 0..3
    const int lane = tid & 63;
    const int qh = lane & 31;                          // MFMA m/n index (32)
    const int hh = lane >> 5;                          // half 0/1
    const int qbase = qt * 128;

    const unsigned short* xbh = xb + (size_t)b * SEQ * DMODEL + h * HD;
    const unsigned short* xTh = xbT + (size_t)bh * HD * SEQ;

    // Q fragments (B-operand): q-row = qbase + w*32 + qh, d = dc*16 + hh*8 + j
    const int qrow = qbase + w * 32 + qh;
    s8v qf0 = *(const s8v*)(xbh + (size_t)qrow * DMODEL + 0 * 16 + hh * 8);
    s8v qf1 = *(const s8v*)(xbh + (size_t)qrow * DMODEL + 1 * 16 + hh * 8);
    s8v qf2 = *(const s8v*)(xbh + (size_t)qrow * DMODEL + 2 * 16 + hh * 8);
    s8v qf3 = *(const s8v*)(xbh + (size_t)qrow * DMODEL + 3 * 16 + hh * 8);

    // K A-frag offsets: row = kb32*32 + qh, chunk (2dc+hh) at XOR slot
    int kbo[2][4];
    // V^T B-frag offsets: row d = db32*32 + qh, k-chunk (2kc+hh)
    int vbo[2][4];
#pragma unroll
    for (int i2 = 0; i2 < 2; ++i2)
#pragma unroll
        for (int c = 0; c < 4; ++c) {
            kbo[i2][c] = (i2 * 32 + qh) * 128 + (((2 * c + hh) ^ (qh & 7)) * 16);
            vbo[i2][c] = 8192 + (i2 * 32 + qh) * 128 + (((2 * c + hh) ^ (qh & 7)) * 16);
        }

    // P scratch (per wave 4KB): [q:32][kgroup:8][16B], slot = group ^ (q&7).
    char* const Pbase = lds + 32768 + w * 4096;
    int pwo0[4], pwo1[4], pro[4];
#pragma unroll
    for (int j2 = 0; j2 < 4; ++j2) {
        pwo0[j2] = qh * 128 + (((j2 + 0) ^ (qh & 7)) * 16) + 8 * hh;
        pwo1[j2] = qh * 128 + (((j2 + 4) ^ (qh & 7)) * 16) + 8 * hh;
        pro[j2]  = qh * 128 + (((2 * j2 + hh) ^ (qh & 7)) * 16);
    }

    f16v o0 = {0,0,0,0,0,0,0,0,0,0,0,0,0,0,0,0};
    f16v o1 = o0;
    float lsum = 0.0f;

    const int sr = lane >> 3;   // staging: row within 8-row chunk
    const int sc = lane & 7;    // staging: 16B slot within row

    // prologue: prefetch tile 0 into buf0
    stage_tile(xbh, xTh, lds, 0, 0, w, sr, sc);

    const int ktEnd = 2 * qt + 1;
    for (int kt = 0; kt <= ktEnd; ++kt) {
        char* const buf = lds + ((kt & 1) << 14);
        // Drains this tile's loads (issued a full iteration ago); also
        // guarantees all waves finished reading buf^1 -> restage race-free.
        __syncthreads();
        if (kt < ktEnd)
            stage_tile(xbh, xTh, lds, ((kt & 1) ^ 1) << 14, (kt + 1) * 64, w, sr, sc);

        const int base_off = qbase + w * 32 - kt * 64;   // wave-uniform
        if (base_off + 31 < 0) continue;                 // tile dead for wave
        const bool fullLive = (base_off >= 63);
        const int qlim = base_off + qh;                  // live iff klocal<=qlim

        // ---- QK^T (A = K rows, B = Q; pre-scaled operands) ----
        f16v c0 = {0,0,0,0,0,0,0,0,0,0,0,0,0,0,0,0};
        f16v c1 = c0;
        __builtin_amdgcn_s_setprio(1);
        c0 = __builtin_amdgcn_mfma_f32_32x32x16_bf16(*(const s8v*)(buf + kbo[0][0]), qf0, c0, 0, 0, 0);
        c0 = __builtin_amdgcn_mfma_f32_32x32x16_bf16(*(const s8v*)(buf + kbo[0][1]), qf1, c0, 0, 0, 0);
        c0 = __builtin_amdgcn_mfma_f32_32x32x16_bf16(*(const s8v*)(buf + kbo[0][2]), qf2, c0, 0, 0, 0);
        c0 = __builtin_amdgcn_mfma_f32_32x32x16_bf16(*(const s8v*)(buf + kbo[0][3]), qf3, c0, 0, 0, 0);
        c1 = __builtin_amdgcn_mfma_f32_32x32x16_bf16(*(const s8v*)(buf + kbo[1][0]), qf0, c1, 0, 0, 0);
        c1 = __builtin_amdgcn_mfma_f32_32x32x16_bf16(*(const s8v*)(buf + kbo[1][1]), qf1, c1, 0, 0, 0);
        c1 = __builtin_amdgcn_mfma_f32_32x32x16_bf16(*(const s8v*)(buf + kbo[1][2]), qf2, c1, 0, 0, 0);
        c1 = __builtin_amdgcn_mfma_f32_32x32x16_bf16(*(const s8v*)(buf + kbo[1][3]), qf3, c1, 0, 0, 0);
        __builtin_amdgcn_s_setprio(0);

        // ---- softmax (no max) + packed P scatter; C row k = (e&3)+8(e>>2)+4hh ----
        float p0[16], p1[16];
#pragma unroll
        for (int e = 0; e < 16; ++e) {
            p0[e] = __builtin_amdgcn_exp2f(c0[e]);
            p1[e] = __builtin_amdgcn_exp2f(c1[e]);
        }
        if (!fullLive) {
#pragma unroll
            for (int e = 0; e < 16; ++e) {
                const int kl = (e & 3) + 8 * (e >> 2) + 4 * hh;
                p0[e] = (kl <= qlim) ? p0[e] : 0.0f;
                p1[e] = (kl + 32 <= qlim) ? p1[e] : 0.0f;
            }
        }
#pragma unroll
        for (int e = 0; e < 16; ++e) lsum += p0[e] + p1[e];
#pragma unroll
        for (int j2 = 0; j2 < 4; ++j2) {
            uint2 u;
            u.x = pk_bf16(p0[4 * j2 + 0], p0[4 * j2 + 1]);
            u.y = pk_bf16(p0[4 * j2 + 2], p0[4 * j2 + 3]);
            *(uint2*)(Pbase + pwo0[j2]) = u;
            u.x = pk_bf16(p1[4 * j2 + 0], p1[4 * j2 + 1]);
            u.y = pk_bf16(p1[4 * j2 + 2], p1[4 * j2 + 3]);
            *(uint2*)(Pbase + pwo1[j2]) = u;
        }

        // ---- PV: A = P (scratch b128), B = V^T frags (shared d-blocks) ----
        const s8v pa0 = *(const s8v*)(Pbase + pro[0]);
        const s8v pa1 = *(const s8v*)(Pbase + pro[1]);
        const s8v pa2 = *(const s8v*)(Pbase + pro[2]);
        const s8v pa3 = *(const s8v*)(Pbase + pro[3]);
        __builtin_amdgcn_s_setprio(1);
        o0 = __builtin_amdgcn_mfma_f32_32x32x16_bf16(pa0, *(const s8v*)(buf + vbo[0][0]), o0, 0, 0, 0);
        o1 = __builtin_amdgcn_mfma_f32_32x32x16_bf16(pa0, *(const s8v*)(buf + vbo[1][0]), o1, 0, 0, 0);
        o0 = __builtin_amdgcn_mfma_f32_32x32x16_bf16(pa1, *(const s8v*)(buf + vbo[0][1]), o0, 0, 0, 0);
        o1 = __builtin_amdgcn_mfma_f32_32x32x16_bf16(pa1, *(const s8v*)(buf + vbo[1][1]), o1, 0, 0, 0);
        o0 = __builtin_amdgcn_mfma_f32_32x32x16_bf16(pa2, *(const s8v*)(buf + vbo[0][2]), o0, 0, 0, 0);
        o1 = __builtin_amdgcn_mfma_f32_32x32x16_bf16(pa2, *(const s8v*)(buf + vbo[1][2]), o1, 0, 0, 0);
        o0 = __builtin_amdgcn_mfma_f32_32x32x16_bf16(pa3, *(const s8v*)(buf + vbo[0][3]), o0, 0, 0, 0);
        o1 = __builtin_amdgcn_mfma_f32_32x32x16_bf16(pa3, *(const s8v*)(buf + vbo[1][3]), o1, 0, 0, 0);
        __builtin_amdgcn_s_setprio(0);
    }

    // ---- epilogue: l[q] = lsum(h0) + lsum(h1); normalize, store ----
    lsum += __shfl_xor(lsum, 32, 64);
    float invr[16];
#pragma unroll
    for (int e = 0; e < 16; ++e) {
        const int rowq = (e & 3) + 8 * (e >> 2) + 4 * hh;
        invr[e] = 1.0f / __shfl(lsum, rowq, 64);
    }

    float* outh = out + (size_t)b * SEQ * DMODEL + h * HD;
#pragma unroll
    for (int e = 0; e < 16; ++e) {
        const int rowq = (e & 3) + 8 * (e >> 2) + 4 * hh;
        const size_t ro = (size_t)(qbase + w * 32 + rowq) * DMODEL;
        outh[ro + 0 * 32 + qh] = o0[e] * invr[e];
        outh[ro + 1 * 32 + qh] = o1[e] * invr[e];
    }
}

// ---------------------------------------------------------------------------
// Fallback (round-1 fp32 kernel, known-correct) if workspace is too small.
// ---------------------------------------------------------------------------
#define KT 32
#define QR 16
#define LDS_STRIDE 68

__global__ __launch_bounds__(64, 2)
void attn_fp32_kernel(const float* __restrict__ x, float* __restrict__ out) {
    __shared__ float kv[KT * LDS_STRIDE];
    const int id = blockIdx.x;
    const int bh = id & (BATCH * NHEAD - 1);
    const int qt = (SEQ / QR - 1) - (id >> 5);
    const int b = bh >> 4, h = bh & (NHEAD - 1);
    const int lane = threadIdx.x;
    const int row = lane & (QR - 1);
    const int slice = lane >> 4;
    const int qrow = qt * QR + row;
    const float* xh = x + (size_t)b * SEQ * DMODEL + (size_t)h * HD;
    float q[HD], o[HD];
    const float4* qp = (const float4*)(xh + (size_t)qrow * DMODEL);
#pragma unroll
    for (int i = 0; i < HD / 4; ++i) {
        float4 v = qp[i];
        q[4*i+0] = v.x * 0.125f; q[4*i+1] = v.y * 0.125f;
        q[4*i+2] = v.z * 0.125f; q[4*i+3] = v.w * 0.125f;
    }
#pragma unroll
    for (int d = 0; d < HD; ++d) o[d] = 0.0f;
    float l = 0.0f;
    const int kend = qt * QR + QR;
    for (int kt0 = 0; kt0 < kend; kt0 += KT) {
        __syncthreads();
#pragma unroll
        for (int i = 0; i < (KT * HD / 4) / 64; ++i) {
            int idx = i * 64 + lane;
            int r = idx >> 4, cc = idx & 15;
            *(float4*)(kv + r * LDS_STRIDE + cc * 4) =
                *(const float4*)(xh + (size_t)(kt0 + r) * DMODEL + cc * 4);
        }
        __syncthreads();
#pragma unroll 2
        for (int jj = 0; jj < KT / 4; ++jj) {
            const int j = jj * 4 + slice;
            const float* kr = kv + j * LDS_STRIDE;
            float a0 = 0.f, a1 = 0.f, a2 = 0.f, a3 = 0.f;
#pragma unroll
            for (int dq = 0; dq < 16; ++dq) {
                float4 kk = ((const float4*)kr)[dq];
                a0 = fmaf(q[4*dq+0], kk.x, a0); a1 = fmaf(q[4*dq+1], kk.y, a1);
                a2 = fmaf(q[4*dq+2], kk.z, a2); a3 = fmaf(q[4*dq+3], kk.w, a3);
            }
            float p = __expf((a0 + a1) + (a2 + a3));
            p = (kt0 + j <= qrow) ? p : 0.0f;
            l += p;
#pragma unroll
            for (int dq = 0; dq < 16; ++dq) {
                float4 vv = ((const float4*)kr)[dq];
                o[4*dq+0] = fmaf(p, vv.x, o[4*dq+0]); o[4*dq+1] = fmaf(p, vv.y, o[4*dq+1]);
                o[4*dq+2] = fmaf(p, vv.z, o[4*dq+2]); o[4*dq+3] = fmaf(p, vv.w, o[4*dq+3]);
            }
        }
    }
    l += __shfl_xor(l, 16, 64);
    l += __shfl_xor(l, 32, 64);
#pragma unroll
    for (int d = 0; d < HD; ++d) {
        o[d] += __shfl_xor(o[d], 16, 64);
        o[d] += __shfl_xor(o[d], 32, 64);
    }
    if (slice == 0) {
        const float invl = 1.0f / l;
        float4* op = (float4*)(out + ((size_t)b * SEQ + qrow) * DMODEL + (size_t)h * HD);
#pragma unroll
        for (int i = 0; i < HD / 4; ++i) {
            float4 v;
            v.x = o[4*i+0] * invl; v.y = o[4*i+1] * invl;
            v.z = o[4*i+2] * invl; v.w = o[4*i+3] * invl;
            op[i] = v;
        }
    }
}

extern "C" void kernel_launch(void* const* d_in, const int* in_sizes, int n_in,
                              void* d_out, int out_size, void* d_ws, size_t ws_size,
                              hipStream_t stream) {
    const float* x = (const float*)d_in[0];
    float* out = (float*)d_out;
    const size_t nXb = (size_t)BATCH * SEQ * DMODEL;            // u16 elems
    const size_t need = 2 * nXb * 2;                            // xb + xbT
    if (ws_size >= need) {
        unsigned short* xb  = (unsigned short*)d_ws;
        unsigned short* xbT = xb + nXb;
        hipLaunchKernelGGL(prep_kernel, dim3(BH * SEQ / 32), dim3(256), 0, stream,
                           x, xb, xbT);
        hipLaunchKernelGGL(flash_kernel, dim3(BH * SEQ / 128), dim3(256), 0, stream,
                           xb, xbT, out);
    } else {
        hipLaunchKernelGGL(attn_fp32_kernel, dim3(BATCH * NHEAD * (SEQ / QR)), dim3(64), 0,
                           stream, x, out);
    }
}

// Round 13
// 104.845 us; speedup vs baseline: 1.0153x; 1.0153x over previous
//
#include <hip/hip_runtime.h>
#include <hip/hip_bf16.h>

#define BATCH  2
#define SEQ    2048
#define DMODEL 1024
#define NHEAD  16
#define HD     64
#define BH     (BATCH * NHEAD)

typedef __attribute__((ext_vector_type(8))) short s8v;    // 8 bf16 = 4 VGPRs (MFMA A/B frag)
typedef __attribute__((ext_vector_type(16))) float f16v;  // 32x32 MFMA C/D frag
typedef __attribute__((ext_vector_type(4))) unsigned u4v; // 4 u32 = one A-frag as words

// sqrt(0.125 * log2(e)): folded QK^T scale (beta^2 = 0.18033688)
#define QK_BETA 0.42466089f

__device__ inline unsigned short bf16_rne(float f) {
    unsigned u = __builtin_bit_cast(unsigned, f);
    u += 0x7FFFu + ((u >> 16) & 1u);
    return (unsigned short)(u >> 16);
}

// pack two f32 -> u32 of 2 bf16 via hardware v_cvt_pk_bf16_f32 (RNE).
// memcpy, not bit_cast (r5: __hip_bfloat162 not trivially copyable here).
__device__ __forceinline__ unsigned pk_bf16(float lo, float hi) {
    __hip_bfloat162 h = __float22bfloat162_rn(make_float2(lo, hi));
    unsigned u;
    __builtin_memcpy(&u, &h, 4);
    return u;
}

// half-wave exchange: after the op a = {a_lo, b_lo}, b = {a_hi, b_hi}
// (lanes 0-31 of a keep a, lanes 32-63 of a get b's lanes 0-31, etc).
// Pure-register VALU op; data-ordered via "+v" constraints (no memory).
__device__ __forceinline__ void pl32swap(unsigned& a, unsigned& b) {
    asm volatile("v_permlane32_swap_b32 %0, %1" : "+v"(a), "+v"(b));
}

// ---------------------------------------------------------------------------
// Prep v4 [verbatim round-11, verified passing]: x fp32 -> xb bf16 scaled by
// QK_BETA (Q/K path) and xbT bf16 unscaled [bh][d][s] (V path).
// ---------------------------------------------------------------------------
__global__ __launch_bounds__(256) void prep_kernel(const float* __restrict__ x,
                                                   unsigned short* __restrict__ xb,
                                                   unsigned short* __restrict__ xbT) {
    __shared__ unsigned short tileT[64 * 40];
    const int id = blockIdx.x;
    const int bh = id & (BH - 1);
    const int st = id >> 5;                    // s-tile 0..63
    const int b = bh >> 4, h = bh & (NHEAD - 1);
    const int s0 = st * 32;
    const int tid = threadIdx.x;
    const int c4 = tid & 15, r16 = tid >> 4;

    const size_t off0 = (size_t)(b * SEQ + s0 + r16) * DMODEL + h * HD + c4 * 4;
    const size_t off1 = (size_t)(b * SEQ + s0 + 16 + r16) * DMODEL + h * HD + c4 * 4;
    const float4 v0 = *(const float4*)(x + off0);
    const float4 v1 = *(const float4*)(x + off1);

    {
        uint2 u;
        u.x = pk_bf16(v0.x * QK_BETA, v0.y * QK_BETA);
        u.y = pk_bf16(v0.z * QK_BETA, v0.w * QK_BETA);
        *(uint2*)(xb + off0) = u;
        u.x = pk_bf16(v1.x * QK_BETA, v1.y * QK_BETA);
        u.y = pk_bf16(v1.z * QK_BETA, v1.w * QK_BETA);
        *(uint2*)(xb + off1) = u;
    }
    {
        const int d0 = c4 * 4;
        unsigned short* t0 = tileT + r16;
        t0[(d0 + 0) * 40] = bf16_rne(v0.x);
        t0[(d0 + 1) * 40] = bf16_rne(v0.y);
        t0[(d0 + 2) * 40] = bf16_rne(v0.z);
        t0[(d0 + 3) * 40] = bf16_rne(v0.w);
        unsigned short* t1 = tileT + 16 + r16;
        t1[(d0 + 0) * 40] = bf16_rne(v1.x);
        t1[(d0 + 1) * 40] = bf16_rne(v1.y);
        t1[(d0 + 2) * 40] = bf16_rne(v1.z);
        t1[(d0 + 3) * 40] = bf16_rne(v1.w);
    }
    __syncthreads();
    {
        const int d = tid >> 2;
        const int sq = (tid & 3) * 8;
        const s8v o = *(const s8v*)(tileT + d * 40 + sq);
        *(s8v*)(xbT + (size_t)(bh * HD + d) * SEQ + s0 + sq) = o;
    }
}

// ---------------------------------------------------------------------------
// Stage one 64x64 K tile + 64x64 V^T tile into LDS buffer at bufoff, with a
// 2-wave block: wave 0 -> K rows, wave 1 -> V^T rows. 8 x global_load_lds(16B)
// per lane. Same protocol as the r1-verified stage_tile (linear LDS dest +
// pre-swizzled global source); coverage bijective: 2 waves x 8 x 64 x 16B=16KB.
// ---------------------------------------------------------------------------
__device__ __forceinline__ void stage_tile2(const unsigned short* __restrict__ xbh,
                                            const unsigned short* __restrict__ xTh,
                                            char* lds, int bufoff, int k0,
                                            int w, int sr, int sc) {
    if (w == 0) {
#pragma unroll
        for (int i = 0; i < 8; ++i) {
            const int r = i * 8 + sr;
            const unsigned short* gsrc =
                xbh + (size_t)(k0 + r) * DMODEL + ((sc ^ (r & 7)) * 8);
            const int loff = __builtin_amdgcn_readfirstlane(bufoff + i * 1024);
            __builtin_amdgcn_global_load_lds(
                (const __attribute__((address_space(1))) void*)gsrc,
                (__attribute__((address_space(3))) void*)(lds + loff), 16, 0, 0);
        }
    } else {
#pragma unroll
        for (int i = 0; i < 8; ++i) {
            const int d = i * 8 + sr;
            const unsigned short* gsrc =
                xTh + (size_t)d * SEQ + k0 + ((sc ^ (d & 7)) * 8);
            const int loff = __builtin_amdgcn_readfirstlane(bufoff + 8192 + i * 1024);
            __builtin_amdgcn_global_load_lds(
                (const __attribute__((address_space(1))) void*)gsrc,
                (__attribute__((address_space(3))) void*)(lds + loff), 16, 0, 0);
        }
    }
}

// ---------------------------------------------------------------------------
// Flash attention, bf16 MFMA 32x32x16, swapped QK^T, P fully IN-REGISTER:
// cvt_pk pairs + v_permlane32_swap_b32 redistribute P into PV A-frags (T12),
// eliminating the per-iteration P-LDS round-trip (write -> lgkmcnt(0) -> read)
// that sat on the serial critical path in r6-r12. LDS = dbuf 2x16K only.
// Geometry = r11 (best verified): 64q tiles, grid 1024, quad-balanced qt map,
// 4 blocks/CU; blocks are 2 waves x 32q. Sync template verbatim r6/r9/r11.
// Mapping proof: lane (qh,hh) holds P[k=i2*32+(e&3)+8(e>>2)+4hh][q=qh];
// PA_{j2} needs P[k=16*j2+8hh+j][q=qh]. With u_{i2}[m]=pk(p[2m],p[2m+1])
// (covers k=8(m>>1)+4hh+2(m&1)+{0,1}), swap(u[4(j2&1)+pi], u[4(j2&1)+2+pi])
// yields words (w_pi, w_{2+pi}) of PA_{j2} for BOTH halves. Cross-checked
// against the r12-verified LDS scratch layout (same mapping, memory form).
// ---------------------------------------------------------------------------
__global__ __launch_bounds__(128, 2) void flash_kernel(const unsigned short* __restrict__ xb,
                                                       const unsigned short* __restrict__ xbT,
                                                       float* __restrict__ out) {
    __shared__ __align__(16) char lds[32768];

    const int id = blockIdx.x;
    const int bh = id & (BH - 1);
    const int t5 = id >> 5;                    // 0..31
    const int rr = t5 >> 3, uu = t5 & 7;
    // quad-balanced (r11-verified): per-CU quad sums to 66 iters
    const int qt = (rr == 0) ? (31 - uu) : (rr == 1) ? (16 + uu)
                 : (rr == 2) ? (15 - uu) : uu;
    const int b = bh >> 4, h = bh & (NHEAD - 1);
    const int tid = threadIdx.x;
    const int w = tid >> 6;                            // wave 0,1
    const int lane = tid & 63;
    const int qh = lane & 31;                          // MFMA m/n index (32)
    const int hh = lane >> 5;                          // half 0/1
    const int qbase = qt * 64;

    const unsigned short* xbh = xb + (size_t)b * SEQ * DMODEL + h * HD;
    const unsigned short* xTh = xbT + (size_t)bh * HD * SEQ;

    // Q fragments (B-operand): q-row = qbase + w*32 + qh, d = c*16 + hh*8 + j
    const int qrow = qbase + w * 32 + qh;
    const s8v qf0 = *(const s8v*)(xbh + (size_t)qrow * DMODEL + 0 * 16 + hh * 8);
    const s8v qf1 = *(const s8v*)(xbh + (size_t)qrow * DMODEL + 1 * 16 + hh * 8);
    const s8v qf2 = *(const s8v*)(xbh + (size_t)qrow * DMODEL + 2 * 16 + hh * 8);
    const s8v qf3 = *(const s8v*)(xbh + (size_t)qrow * DMODEL + 3 * 16 + hh * 8);

    // K A-frag / V^T B-frag LDS byte offsets (r12-verified formulas)
    int kbo[2][4], vbo[2][4];
#pragma unroll
    for (int i2 = 0; i2 < 2; ++i2)
#pragma unroll
        for (int c = 0; c < 4; ++c) {
            kbo[i2][c] = (i2 * 32 + qh) * 128 + (((2 * c + hh) ^ (qh & 7)) * 16);
            vbo[i2][c] = 8192 + (i2 * 32 + qh) * 128 + (((2 * c + hh) ^ (qh & 7)) * 16);
        }

    f16v o0 = {0,0,0,0,0,0,0,0,0,0,0,0,0,0,0,0};
    f16v o1 = o0;
    float lsum = 0.0f;

    const int sr = lane >> 3;   // staging: row within 8-row chunk
    const int sc = lane & 7;    // staging: 16B slot within row

    // prologue: prefetch tile 0 into buf0
    stage_tile2(xbh, xTh, lds, 0, 0, w, sr, sc);

    for (int kt = 0; kt <= qt; ++kt) {
        char* const buf = lds + ((kt & 1) << 14);
        // Drains this tile's loads (issued a full iteration ago); also
        // guarantees all waves finished reading buf^1 -> restage race-free.
        __syncthreads();
        if (kt < qt)
            stage_tile2(xbh, xTh, lds, ((kt & 1) ^ 1) << 14, (kt + 1) * 64, w, sr, sc);

        const int base_off = qbase + w * 32 - kt * 64;   // wave-uniform, >= 0
        const bool fullLive = (base_off >= 63);
        const int qlim = base_off + qh;                  // live iff klocal<=qlim

        // ---- QK^T (A = K rows, B = Q; pre-scaled operands) ----
        f16v c0 = {0,0,0,0,0,0,0,0,0,0,0,0,0,0,0,0};
        f16v c1 = c0;
        __builtin_amdgcn_s_setprio(1);
        c0 = __builtin_amdgcn_mfma_f32_32x32x16_bf16(*(const s8v*)(buf + kbo[0][0]), qf0, c0, 0, 0, 0);
        c0 = __builtin_amdgcn_mfma_f32_32x32x16_bf16(*(const s8v*)(buf + kbo[0][1]), qf1, c0, 0, 0, 0);
        c0 = __builtin_amdgcn_mfma_f32_32x32x16_bf16(*(const s8v*)(buf + kbo[0][2]), qf2, c0, 0, 0, 0);
        c0 = __builtin_amdgcn_mfma_f32_32x32x16_bf16(*(const s8v*)(buf + kbo[0][3]), qf3, c0, 0, 0, 0);
        c1 = __builtin_amdgcn_mfma_f32_32x32x16_bf16(*(const s8v*)(buf + kbo[1][0]), qf0, c1, 0, 0, 0);
        c1 = __builtin_amdgcn_mfma_f32_32x32x16_bf16(*(const s8v*)(buf + kbo[1][1]), qf1, c1, 0, 0, 0);
        c1 = __builtin_amdgcn_mfma_f32_32x32x16_bf16(*(const s8v*)(buf + kbo[1][2]), qf2, c1, 0, 0, 0);
        c1 = __builtin_amdgcn_mfma_f32_32x32x16_bf16(*(const s8v*)(buf + kbo[1][3]), qf3, c1, 0, 0, 0);
        __builtin_amdgcn_s_setprio(0);

        // ---- softmax (no max); C row k = (e&3)+8(e>>2)+4hh ----
        float p0[16], p1[16];
#pragma unroll
        for (int e = 0; e < 16; ++e) {
            p0[e] = __builtin_amdgcn_exp2f(c0[e]);
            p1[e] = __builtin_amdgcn_exp2f(c1[e]);
        }
        if (!fullLive) {   // wave-uniform: only the diagonal k-tile
#pragma unroll
            for (int e = 0; e < 16; ++e) {
                const int kl = (e & 3) + 8 * (e >> 2) + 4 * hh;
                p0[e] = (kl <= qlim) ? p0[e] : 0.0f;
                p1[e] = (kl + 32 <= qlim) ? p1[e] : 0.0f;
            }
        }
#pragma unroll
        for (int e = 0; e < 16; ++e) lsum += p0[e] + p1[e];

        // ---- P -> bf16 pairs in-register ----
        unsigned u0[8], u1[8];
#pragma unroll
        for (int m = 0; m < 8; ++m) {
            u0[m] = pk_bf16(p0[2 * m], p0[2 * m + 1]);
            u1[m] = pk_bf16(p1[2 * m], p1[2 * m + 1]);
        }
        // ---- T12 half-wave redistribution: 8 swaps -> 4 A-frags ----
        u4v pw0, pw1, pw2, pw3;
        {
            unsigned a, b2;
            a = u0[0]; b2 = u0[2]; pl32swap(a, b2); pw0[0] = a; pw0[2] = b2;
            a = u0[1]; b2 = u0[3]; pl32swap(a, b2); pw0[1] = a; pw0[3] = b2;
            a = u0[4]; b2 = u0[6]; pl32swap(a, b2); pw1[0] = a; pw1[2] = b2;
            a = u0[5]; b2 = u0[7]; pl32swap(a, b2); pw1[1] = a; pw1[3] = b2;
            a = u1[0]; b2 = u1[2]; pl32swap(a, b2); pw2[0] = a; pw2[2] = b2;
            a = u1[1]; b2 = u1[3]; pl32swap(a, b2); pw2[1] = a; pw2[3] = b2;
            a = u1[4]; b2 = u1[6]; pl32swap(a, b2); pw3[0] = a; pw3[2] = b2;
            a = u1[5]; b2 = u1[7]; pl32swap(a, b2); pw3[1] = a; pw3[3] = b2;
        }
        const s8v pa0 = __builtin_bit_cast(s8v, pw0);
        const s8v pa1 = __builtin_bit_cast(s8v, pw1);
        const s8v pa2 = __builtin_bit_cast(s8v, pw2);
        const s8v pa3 = __builtin_bit_cast(s8v, pw3);

        // ---- PV: A = P (registers), B = V^T frags ----
        __builtin_amdgcn_s_setprio(1);
        o0 = __builtin_amdgcn_mfma_f32_32x32x16_bf16(pa0, *(const s8v*)(buf + vbo[0][0]), o0, 0, 0, 0);
        o1 = __builtin_amdgcn_mfma_f32_32x32x16_bf16(pa0, *(const s8v*)(buf + vbo[1][0]), o1, 0, 0, 0);
        o0 = __builtin_amdgcn_mfma_f32_32x32x16_bf16(pa1, *(const s8v*)(buf + vbo[0][1]), o0, 0, 0, 0);
        o1 = __builtin_amdgcn_mfma_f32_32x32x16_bf16(pa1, *(const s8v*)(buf + vbo[1][1]), o1, 0, 0, 0);
        o0 = __builtin_amdgcn_mfma_f32_32x32x16_bf16(pa2, *(const s8v*)(buf + vbo[0][2]), o0, 0, 0, 0);
        o1 = __builtin_amdgcn_mfma_f32_32x32x16_bf16(pa2, *(const s8v*)(buf + vbo[1][2]), o1, 0, 0, 0);
        o0 = __builtin_amdgcn_mfma_f32_32x32x16_bf16(pa3, *(const s8v*)(buf + vbo[0][3]), o0, 0, 0, 0);
        o1 = __builtin_amdgcn_mfma_f32_32x32x16_bf16(pa3, *(const s8v*)(buf + vbo[1][3]), o1, 0, 0, 0);
        __builtin_amdgcn_s_setprio(0);
    }

    // ---- epilogue: l[q] = lsum(h0)+lsum(h1); lanes 0..31 hold l[qh] ----
    lsum += __shfl_xor(lsum, 32, 64);
    float invr[16];
#pragma unroll
    for (int e = 0; e < 16; ++e) {
        const int rowq = (e & 3) + 8 * (e >> 2) + 4 * hh;
        invr[e] = 1.0f / __shfl(lsum, rowq, 64);
    }

    float* outh = out + (size_t)b * SEQ * DMODEL + h * HD;
#pragma unroll
    for (int e = 0; e < 16; ++e) {
        const int rowq = (e & 3) + 8 * (e >> 2) + 4 * hh;
        const size_t ro = (size_t)(qbase + w * 32 + rowq) * DMODEL;
        outh[ro + 0 * 32 + qh] = o0[e] * invr[e];
        outh[ro + 1 * 32 + qh] = o1[e] * invr[e];
    }
}

// ---------------------------------------------------------------------------
// Fallback (round-1 fp32 kernel, known-correct) if workspace is too small.
// ---------------------------------------------------------------------------
#define KT 32
#define QR 16
#define LDS_STRIDE 68

__global__ __launch_bounds__(64, 2)
void attn_fp32_kernel(const float* __restrict__ x, float* __restrict__ out) {
    __shared__ float kv[KT * LDS_STRIDE];
    const int id = blockIdx.x;
    const int bh = id & (BATCH * NHEAD - 1);
    const int qt = (SEQ / QR - 1) - (id >> 5);
    const int b = bh >> 4, h = bh & (NHEAD - 1);
    const int lane = threadIdx.x;
    const int row = lane & (QR - 1);
    const int slice = lane >> 4;
    const int qrow = qt * QR + row;
    const float* xh = x + (size_t)b * SEQ * DMODEL + (size_t)h * HD;
    float q[HD], o[HD];
    const float4* qp = (const float4*)(xh + (size_t)qrow * DMODEL);
#pragma unroll
    for (int i = 0; i < HD / 4; ++i) {
        float4 v = qp[i];
        q[4*i+0] = v.x * 0.125f; q[4*i+1] = v.y * 0.125f;
        q[4*i+2] = v.z * 0.125f; q[4*i+3] = v.w * 0.125f;
    }
#pragma unroll
    for (int d = 0; d < HD; ++d) o[d] = 0.0f;
    float l = 0.0f;
    const int kend = qt * QR + QR;
    for (int kt0 = 0; kt0 < kend; kt0 += KT) {
        __syncthreads();
#pragma unroll
        for (int i = 0; i < (KT * HD / 4) / 64; ++i) {
            int idx = i * 64 + lane;
            int r = idx >> 4, cc = idx & 15;
            *(float4*)(kv + r * LDS_STRIDE + cc * 4) =
                *(const float4*)(xh + (size_t)(kt0 + r) * DMODEL + cc * 4);
        }
        __syncthreads();
#pragma unroll 2
        for (int jj = 0; jj < KT / 4; ++jj) {
            const int j = jj * 4 + slice;
            const float* kr = kv + j * LDS_STRIDE;
            float a0 = 0.f, a1 = 0.f, a2 = 0.f, a3 = 0.f;
#pragma unroll
            for (int dq = 0; dq < 16; ++dq) {
                float4 kk = ((const float4*)kr)[dq];
                a0 = fmaf(q[4*dq+0], kk.x, a0); a1 = fmaf(q[4*dq+1], kk.y, a1);
                a2 = fmaf(q[4*dq+2], kk.z, a2); a3 = fmaf(q[4*dq+3], kk.w, a3);
            }
            float p = __expf((a0 + a1) + (a2 + a3));
            p = (kt0 + j <= qrow) ? p : 0.0f;
            l += p;
#pragma unroll
            for (int dq = 0; dq < 16; ++dq) {
                float4 vv = ((const float4*)kr)[dq];
                o[4*dq+0] = fmaf(p, vv.x, o[4*dq+0]); o[4*dq+1] = fmaf(p, vv.y, o[4*dq+1]);
                o[4*dq+2] = fmaf(p, vv.z, o[4*dq+2]); o[4*dq+3] = fmaf(p, vv.w, o[4*dq+3]);
            }
        }
    }
    l += __shfl_xor(l, 16, 64);
    l += __shfl_xor(l, 32, 64);
#pragma unroll
    for (int d = 0; d < HD; ++d) {
        o[d] += __shfl_xor(o[d], 16, 64);
        o[d] += __shfl_xor(o[d], 32, 64);
    }
    if (slice == 0) {
        const float invl = 1.0f / l;
        float4* op = (float4*)(out + ((size_t)b * SEQ + qrow) * DMODEL + (size_t)h * HD);
#pragma unroll
        for (int i = 0; i < HD / 4; ++i) {
            float4 v;
            v.x = o[4*i+0] * invl; v.y = o[4*i+1] * invl;
            v.z = o[4*i+2] * invl; v.w = o[4*i+3] * invl;
            op[i] = v;
        }
    }
}

extern "C" void kernel_launch(void* const* d_in, const int* in_sizes, int n_in,
                              void* d_out, int out_size, void* d_ws, size_t ws_size,
                              hipStream_t stream) {
    const float* x = (const float*)d_in[0];
    float* out = (float*)d_out;
    const size_t nXb = (size_t)BATCH * SEQ * DMODEL;            // u16 elems
    const size_t need = 2 * nXb * 2;                            // xb + xbT
    if (ws_size >= need) {
        unsigned short* xb  = (unsigned short*)d_ws;
        unsigned short* xbT = xb + nXb;
        hipLaunchKernelGGL(prep_kernel, dim3(BH * SEQ / 32), dim3(256), 0, stream,
                           x, xb, xbT);
        hipLaunchKernelGGL(flash_kernel, dim3(BH * SEQ / 64), dim3(128), 0, stream,
                           xb, xbT, out);
    } else {
        hipLaunchKernelGGL(attn_fp32_kernel, dim3(BATCH * NHEAD * (SEQ / QR)), dim3(64), 0,
                           stream, x, out);
    }
}